// Round 6
// baseline (669.933 us; speedup 1.0000x reference)
//
#include <hip/hip_runtime.h>
#include <cmath>

// DarwinianRouter r10 — r9 diagnostic resubmit (r9 died to container infra,
// audit found no fault path; round-1 precedent: verbatim resubmit passed).
// Change vs r9: REPEAT 3 -> 5 so gemm (5x duration >= 225us) is GUARANTEED
// above the ~159us fill cutoff and lands in the rocprof top-5 with counters.
// Structure: K=256 double-buffered LDS slabs staged via global_load_lds
// (linear dest + XOR-swizzled global src; ds_read applies same swizzle),
// 8 waves share slab, wave w consumes k = s*256 + w*32 + [0,32).
// dur_us this round is sacrificial (~386 + 4g).

#define N_TOKENS 16384
#define DIM      4096
#define NE       64
#define TOPK     8
#define SCALE    5.0f
#define EPS      1e-12f
#define NSLAB    16        // K slabs of 256
#define REPEAT   5         // diagnostic multiplier (revert to 1 next round)

typedef short  frag   __attribute__((ext_vector_type(8)));   // 8 bf16 bit-patterns
typedef float  f32x16 __attribute__((ext_vector_type(16))); // 32x32 C/D
typedef int    i32x4  __attribute__((ext_vector_type(4)));

__device__ __forceinline__ void split3(float v, unsigned& h1, unsigned& h2, unsigned& h3) {
    unsigned u  = __builtin_bit_cast(unsigned, v);
    unsigned r1 = (u + 0x7FFFu + ((u >> 16) & 1u)) & 0xFFFF0000u;
    float    d1 = v - __builtin_bit_cast(float, r1);
    unsigned w  = __builtin_bit_cast(unsigned, d1);
    unsigned r2 = (w + 0x7FFFu + ((w >> 16) & 1u)) & 0xFFFF0000u;
    float    d2 = d1 - __builtin_bit_cast(float, r2);
    unsigned z  = __builtin_bit_cast(unsigned, d2);
    unsigned r3 = (z + 0x7FFFu + ((z >> 16) & 1u)) & 0xFFFF0000u;
    h1 = r1 >> 16; h2 = r2 >> 16; h3 = r3 >> 16;
}

// sig split + repack, frag-coalesced layout: plane[tile(2)][kb(256)][lane(64)][8],
// lane = (hf<<5)|e31; element (lane,i) = split(sig[e=tile*32+e31][k=kb*16+hf*8+i]).
__launch_bounds__(256)
__global__ void convert_sig(const float* __restrict__ sig,
                            short* __restrict__ h1,
                            short* __restrict__ h2,
                            short* __restrict__ h3) {
    const int tid  = blockIdx.x * 256 + threadIdx.x;   // 32768 threads (128 blocks)
    const int lane = tid & 63;
    const int kb   = (tid >> 6) & 255;
    const int tile = tid >> 14;
    const int e31  = lane & 31, hf = lane >> 5;
    const float* src = sig + (size_t)(tile * 32 + e31) * DIM + kb * 16 + hf * 8;
    const float4 v0 = *(const float4*)(src);
    const float4 v1 = *(const float4*)(src + 4);
    const float vs[8] = {v0.x, v0.y, v0.z, v0.w, v1.x, v1.y, v1.z, v1.w};
    frag o1, o2, o3;
#pragma unroll
    for (int p = 0; p < 8; ++p) {
        unsigned a, b, c;
        split3(vs[p], a, b, c);
        o1[p] = (short)a; o2[p] = (short)b; o3[p] = (short)c;
    }
    const int base = ((tile * 256 + kb) * 64 + lane) * 8;
    *(frag*)(h1 + base) = o1;
    *(frag*)(h2 + base) = o2;
    *(frag*)(h3 + base) = o3;
}

// stage one 32KB slab (32 rows x 256 floats) into LDS: linear dest (HW rule),
// XOR-swizzled GLOBAL source. slot i = cc*512 + w*64 + lane; row r = i>>6
// (= cc*8 + w, wave-uniform), in-row 16B-slot p = i&63 holds global chunk
// p ^ (r&7).
__device__ __forceinline__ void stage_slab256(const float* __restrict__ x, int tb,
                                              int kcol, float* dst, int w, int lane) {
#pragma unroll
    for (int cc = 0; cc < 4; ++cc) {
        const int i = cc * 512 + w * 64 + lane;
        const int r = i >> 6;
        const int j = (i & 63) ^ (r & 7);
        const float* g = x + (size_t)(tb + r) * DIM + kcol + 4 * j;
        float* l = dst + (size_t)(cc * 512 + w * 64) * 4;   // wave-uniform base
        __builtin_amdgcn_global_load_lds(
            (const __attribute__((address_space(1))) void*)g,
            (__attribute__((address_space(3))) void*)l, 16, 0, 0);
    }
}

// grid N_TOKENS/32 blocks x 512 threads (8 waves). Block owns 32 tokens,
// K=4096 in 16 shared slabs of 256; wave w handles k = s*256 + w*32 + [0,32)
// as two 16-wide MFMA steps per slab.
__launch_bounds__(512, 4)
__global__ void gemm_fused(const float* __restrict__ x,
                           const short* __restrict__ sh1,
                           const short* __restrict__ sh2,
                           const short* __restrict__ sh3,
                           float* __restrict__ outR,
                           float* __restrict__ outW,
                           float* __restrict__ outI) {
    // union: slab[2][8192] f32 (64KB, main loop) / epilogue structs (44.7KB)
    __shared__ __align__(16) char smem[65536];
    float* slab = (float*)smem;
    float (*red)[64][34] = (float(*)[64][34])smem;            // [4][64][34]
    float (*res)[68]     = (float(*)[68])(smem + 34816);      // [32][68]
    float (*sqred)[32]   = (float(*)[32])(smem + 43520);      // [8][32]
    float* scl           = (float*)(smem + 44544);            // [32]

    const int t    = threadIdx.x;
    const int lane = t & 63;
    const int w    = t >> 6;
    const int l31  = lane & 31;
    const int half = lane >> 5;

    const int tb = blockIdx.x * 32;
    const int TILE1 = 256 * 64 * 8;     // B-plane tile stride (experts 32..63)
    const int SLABB = 16 * 64 * 8;      // B advance per slab (16 kbs)

    // swizzled LDS read pieces: row rr, 16B-chunks cA(st) = 8w + 4st + 2half
    const int rr = l31;
    const int sw = rr & 7;
    const int roff = rr * 256;

    f32x16 c0 = {};   // experts 0..31
    f32x16 c1 = {};   // experts 32..63
    float sq = 0.f;

#pragma unroll 1
    for (int rep = 0; rep < REPEAT; ++rep) {
        // keep-live reset (rule #17: *=0.0f forces prior rep's values live;
        // bit-exact for finite data, so REPEAT doesn't change results)
        c0 *= 0.0f; c1 *= 0.0f; sq *= 0.0f;

        const short* b1p = sh1 + ((size_t)(w * 2) * 64 + lane) * 8;
        const short* b2p = sh2 + ((size_t)(w * 2) * 64 + lane) * 8;
        const short* b3p = sh3 + ((size_t)(w * 2) * 64 + lane) * 8;

        stage_slab256(x, tb, 0, slab, w, lane);
        __syncthreads();   // slab 0 resident

#pragma unroll 1
        for (int s = 0; s < NSLAB; ++s) {
            const int b = s & 1;
            if (s + 1 < NSLAB)
                stage_slab256(x, tb, (s + 1) * 256, slab + (1 - b) * 8192, w, lane);

            const float* base = slab + b * 8192 + roff;

#pragma unroll
            for (int st = 0; st < 2; ++st) {
                const int so = st * 512;   // B step offset (one kb)
                const frag b1a = *(const frag*)(b1p + so);
                const frag b1b = *(const frag*)(b1p + so + TILE1);
                const frag b2a = *(const frag*)(b2p + so);
                const frag b2b = *(const frag*)(b2p + so + TILE1);
                const frag b3a = *(const frag*)(b3p + so);
                const frag b3b = *(const frag*)(b3p + so + TILE1);

                const int cA = 8 * w + 4 * st + 2 * half;
                const float4 va = *(const float4*)(base + (cA ^ sw) * 4);
                const float4 vb = *(const float4*)(base + ((cA + 1) ^ sw) * 4);

                const float vals[8] = {va.x, va.y, va.z, va.w,
                                       vb.x, vb.y, vb.z, vb.w};
                i32x4 a1i, a2i, a3i;
#pragma unroll
                for (int p = 0; p < 4; ++p) {
                    const float v0 = vals[2 * p], v1 = vals[2 * p + 1];
                    sq = fmaf(v0, v0, sq);
                    sq = fmaf(v1, v1, sq);
                    unsigned h10, h20, h30, h11, h21, h31;
                    split3(v0, h10, h20, h30);
                    split3(v1, h11, h21, h31);
                    a1i[p] = (int)(h10 | (h11 << 16));
                    a2i[p] = (int)(h20 | (h21 << 16));
                    a3i[p] = (int)(h30 | (h31 << 16));
                }
                const frag A1 = __builtin_bit_cast(frag, a1i);
                const frag A2 = __builtin_bit_cast(frag, a2i);
                const frag A3 = __builtin_bit_cast(frag, a3i);

                // 6 products/tile: h1h1 + (h1h2+h2h1) + (h1h3+h3h1+h2h2)
                c0 = __builtin_amdgcn_mfma_f32_32x32x16_bf16(A1, b1a, c0, 0, 0, 0);
                c1 = __builtin_amdgcn_mfma_f32_32x32x16_bf16(A1, b1b, c1, 0, 0, 0);
                c0 = __builtin_amdgcn_mfma_f32_32x32x16_bf16(A1, b2a, c0, 0, 0, 0);
                c1 = __builtin_amdgcn_mfma_f32_32x32x16_bf16(A1, b2b, c1, 0, 0, 0);
                c0 = __builtin_amdgcn_mfma_f32_32x32x16_bf16(A2, b1a, c0, 0, 0, 0);
                c1 = __builtin_amdgcn_mfma_f32_32x32x16_bf16(A2, b1b, c1, 0, 0, 0);
                c0 = __builtin_amdgcn_mfma_f32_32x32x16_bf16(A1, b3a, c0, 0, 0, 0);
                c1 = __builtin_amdgcn_mfma_f32_32x32x16_bf16(A1, b3b, c1, 0, 0, 0);
                c0 = __builtin_amdgcn_mfma_f32_32x32x16_bf16(A3, b1a, c0, 0, 0, 0);
                c1 = __builtin_amdgcn_mfma_f32_32x32x16_bf16(A3, b1b, c1, 0, 0, 0);
                c0 = __builtin_amdgcn_mfma_f32_32x32x16_bf16(A2, b2a, c0, 0, 0, 0);
                c1 = __builtin_amdgcn_mfma_f32_32x32x16_bf16(A2, b2b, c1, 0, 0, 0);
            }

            b1p += SLABB; b2p += SLABB; b3p += SLABB;
            __syncthreads();   // slab s+1 resident; slab s reads complete
        }
    }

    // per-token partial sumsq (lanes l and l+32 share a token)
    sq += __shfl_xor(sq, 32);
    if (lane < 32) sqred[w][l31] = sq;

    // stage 1: waves 4..7 deposit (slab LDS dead; red/res alias it)
    if (w >= 4) {
#pragma unroll
        for (int r = 0; r < 16; ++r) {
            red[w - 4][lane][r]      = c0[r];
            red[w - 4][lane][16 + r] = c1[r];
        }
    }
    __syncthreads();

    // L2-norm scale per token (full K)
    if (t < 32) {
        float q = 0.f;
#pragma unroll
        for (int ww = 0; ww < 8; ++ww) q += sqred[ww][t];
        scl[t] = SCALE / fmaxf(sqrtf(q), EPS);
    }

    // stage 2: waves 0..3 fold their registers in (thread-private cells)
    if (w < 4) {
#pragma unroll
        for (int r = 0; r < 16; ++r) {
            red[w][lane][r]      = c0[r] + red[w][lane][r];
            red[w][lane][16 + r] = c1[r] + red[w][lane][16 + r];
        }
    }
    __syncthreads();

    // gather: wave w owns regs R = 4w..4w+3 (= 16*tile + 4*wm + j);
    // token=(R&3)+8*((R&15)>>2)+4*half, expert = l31 + 32*tile
    const int wm = w & 3, tile = w >> 2;
    const int et = l31 + 32 * tile;
#pragma unroll
    for (int j = 0; j < 4; ++j) {
        const int R = 4 * w + j;
        const float a = red[0][lane][R] + red[1][lane][R] +
                        red[2][lane][R] + red[3][lane][R];
        const int token = j + 8 * wm + 4 * half;
        res[token][et] = a * scl[token];
    }
    __syncthreads();

    // coalesced outR write: thread t -> token t>>4, float4 quad t&15
    {
        const int token = t >> 4, q4 = (t & 15) * 4;
        *(float4*)(outR + (size_t)(tb + token) * NE + q4) =
            *(const float4*)(&res[token][q4]);
    }

    // fused top-8: wave w handles tokens 4w..4w+3.
    // 64-bit key = sortable(f32)<<32 | (63-e): max-reduce = highest value,
    // ties -> lowest expert index (= jax.lax.top_k order).
#pragma unroll 1
    for (int tt = 0; tt < 4; ++tt) {
        const int token = 4 * w + tt;
        const float v = res[token][lane];
        const unsigned u = __builtin_bit_cast(unsigned, v);
        const unsigned sbits = u ^ ((unsigned)(((int)u) >> 31) | 0x80000000u);
        unsigned long long cur = ((unsigned long long)sbits << 32) | (unsigned)(63 - lane);

        float bw = 0.f;
        int   bi = 0;
#pragma unroll
        for (int m = 0; m < TOPK; ++m) {
            unsigned long long r = cur;
#pragma unroll
            for (int d = 32; d >= 1; d >>= 1) {
                const unsigned long long o = __shfl_xor(r, d);
                r = (o > r) ? o : r;
            }
            const int we = 63 - (int)(r & 63ull);   // uniform across wave
            const float bv = __shfl(v, we);
            if (lane == we) cur = 0ull;             // remove winner
            if (lane == m) { bw = bv; bi = we; }
        }
        if (lane < TOPK) {
            const size_t ob = (size_t)(tb + token) * TOPK + lane;
            outW[ob] = log1pf(expf(bw));
            outI[ob] = (float)bi;
        }
    }
}

extern "C" void kernel_launch(void* const* d_in, const int* in_sizes, int n_in,
                              void* d_out, int out_size, void* d_ws, size_t ws_size,
                              hipStream_t stream) {
    const float* x   = (const float*)d_in[0];
    const float* sig = (const float*)d_in[1];
    float* out  = (float*)d_out;
    float* outW = out;
    float* outI = out + (size_t)N_TOKENS * TOPK;
    float* outR = out + (size_t)N_TOKENS * TOPK * 2;

    const size_t SIGE = (size_t)NE * DIM;   // 262144 elems per plane
    short* sh1 = (short*)d_ws;              // 3 planes = 1.5 MB total
    short* sh2 = sh1 + SIGE;
    short* sh3 = sh2 + SIGE;

    convert_sig<<<128, 256, 0, stream>>>(sig, sh1, sh2, sh3);
    gemm_fused<<<N_TOKENS / 32, 512, 0, stream>>>(x, sh1, sh2, sh3, outR, outW, outI);
}

// Round 7
// 391.076 us; speedup vs baseline: 1.7131x; 1.7131x over previous
//
#include <hip/hip_runtime.h>
#include <cmath>

// DarwinianRouter r11.
// r10 counters (REPEAT=5): gemm 88us/rep, VALUBusy 37%, MfmaUtil 25%, HBM 21%,
// 4 waves/SIMD. => ~60% issue-busy (VALU-heavy) + 40% stall; HBM idle. Fixes:
// (1) cheap split: round-half-up (u+0x8000)&mask for h1/h2, truncate h3,
//     shr/and/or packing (~23 ops/pair vs 39). Residual 2^-26 -> ~2^-24, still
//     below the fp32-reassoc noise that already passes at absmax 2^-8.
// (2) 3-buffer K=128 pipeline, raw s_barrier (no vmcnt(0) drain). vmcnt
//     retires IN ORDER (m135): issue order stage(s+1)..B(s)..stage(s+2) means
//     the compiler's own B-frag waits subsume stage readiness; stage loads
//     stay in flight across barriers. Explicit vmcnt(2) + sched_barrier(0)
//     fences as safety (rule #18).
// Predicted: gemm ~45-60us, total ~270-300us, absmax ~2^-8.

#define N_TOKENS 16384
#define DIM      4096
#define NE       64
#define TOPK     8
#define SCALE    5.0f
#define EPS      1e-12f
#define NSLAB    32        // K slabs of 128

typedef short  frag   __attribute__((ext_vector_type(8)));   // 8 bf16 bit-patterns
typedef float  f32x16 __attribute__((ext_vector_type(16)));  // 32x32 C/D
typedef int    i32x4  __attribute__((ext_vector_type(4)));

// cheap 3-plane split: h1,h2 round-half-up (2 ops each), h3 = truncation (0 ops).
// d-subtractions are exact. |res| <~ 3*2^-24 |v|.
__device__ __forceinline__ void split3c(float v, unsigned& r1, unsigned& r2, unsigned& z) {
    unsigned u  = __builtin_bit_cast(unsigned, v);
    r1 = (u + 0x8000u) & 0xFFFF0000u;
    float d1 = v - __builtin_bit_cast(float, r1);
    unsigned w = __builtin_bit_cast(unsigned, d1);
    r2 = (w + 0x8000u) & 0xFFFF0000u;
    float d2 = d1 - __builtin_bit_cast(float, r2);
    z  = __builtin_bit_cast(unsigned, d2);
}

// sig split + repack, frag-coalesced layout: plane[tile(2)][kb(256)][lane(64)][8],
// lane = (hf<<5)|e31; element (lane,i) = split(sig[e=tile*32+e31][k=kb*16+hf*8+i]).
__launch_bounds__(256)
__global__ void convert_sig(const float* __restrict__ sig,
                            short* __restrict__ h1,
                            short* __restrict__ h2,
                            short* __restrict__ h3) {
    const int tid  = blockIdx.x * 256 + threadIdx.x;   // 32768 threads (128 blocks)
    const int lane = tid & 63;
    const int kb   = (tid >> 6) & 255;
    const int tile = tid >> 14;
    const int e31  = lane & 31, hf = lane >> 5;
    const float* src = sig + (size_t)(tile * 32 + e31) * DIM + kb * 16 + hf * 8;
    const float4 v0 = *(const float4*)(src);
    const float4 v1 = *(const float4*)(src + 4);
    const float vs[8] = {v0.x, v0.y, v0.z, v0.w, v1.x, v1.y, v1.z, v1.w};
    frag o1, o2, o3;
#pragma unroll
    for (int p = 0; p < 8; ++p) {
        unsigned a, b, c;
        split3c(vs[p], a, b, c);
        o1[p] = (short)(a >> 16); o2[p] = (short)(b >> 16); o3[p] = (short)(c >> 16);
    }
    const int base = ((tile * 256 + kb) * 64 + lane) * 8;
    *(frag*)(h1 + base) = o1;
    *(frag*)(h2 + base) = o2;
    *(frag*)(h3 + base) = o3;
}

// stage one 16KB slab (32 rows x 128 floats) into LDS: linear dest (HW rule),
// XOR-swizzled GLOBAL source. slot i = cc*512 + w*64 + lane; row r = i>>5,
// in-row 16B-chunk c = i&31 holds global chunk c ^ (r&7).
__device__ __forceinline__ void stage_slab128(const float* __restrict__ x, int tb,
                                              int kcol, float* dst, int w, int lane) {
#pragma unroll
    for (int cc = 0; cc < 2; ++cc) {
        const int i = cc * 512 + w * 64 + lane;
        const int r = i >> 5;
        const int j = (i & 31) ^ (r & 7);
        const float* g = x + (size_t)(tb + r) * DIM + kcol + 4 * j;
        float* l = dst + (size_t)(cc * 512 + w * 64) * 4;   // wave-uniform base
        __builtin_amdgcn_global_load_lds(
            (const __attribute__((address_space(1))) void*)g,
            (__attribute__((address_space(3))) void*)l, 16, 0, 0);
    }
}

// grid N_TOKENS/32 blocks x 512 threads (8 waves). Block owns 32 tokens,
// K=4096 in 32 slabs of 128; wave w handles k = s*128 + w*16 + [0,16) = one
// MFMA step per slab. 3-buffer pipeline: compute(s) || stage(s+2) in flight.
__launch_bounds__(512, 4)
__global__ void gemm_fused(const float* __restrict__ x,
                           const short* __restrict__ sh1,
                           const short* __restrict__ sh2,
                           const short* __restrict__ sh3,
                           float* __restrict__ outR,
                           float* __restrict__ outW,
                           float* __restrict__ outI) {
    // union: slab[3][4096] f32 (48KB, main loop) / epilogue structs (44.7KB)
    __shared__ __align__(16) char smem[49152];
    float* slab = (float*)smem;
    float (*red)[64][34] = (float(*)[64][34])smem;            // [4][64][34]
    float (*res)[68]     = (float(*)[68])(smem + 34816);      // [32][68]
    float (*sqred)[32]   = (float(*)[32])(smem + 43520);      // [8][32]
    float* scl           = (float*)(smem + 44544);            // [32]

    const int t    = threadIdx.x;
    const int lane = t & 63;
    const int w    = t >> 6;
    const int l31  = lane & 31;
    const int half = lane >> 5;

    const int tb = blockIdx.x * 32;
    const int TILE1 = 256 * 64 * 8;     // B-plane tile stride (experts 32..63)
    const int SLABB = 8 * 64 * 8;       // B advance per slab (8 kbs)

    // B: kb = 8s + w; per-wave frag base
    const short* b1p = sh1 + ((size_t)(w * 64) + lane) * 8;
    const short* b2p = sh2 + ((size_t)(w * 64) + lane) * 8;
    const short* b3p = sh3 + ((size_t)(w * 64) + lane) * 8;

    // swizzled LDS read pieces: row rr, 16B-chunks cA = 4w + 2half + {0,1}
    const int rr = l31;
    const int sw = rr & 7;
    const int roff = rr * 128;
    const int cA = 4 * w + 2 * half;

    f32x16 c0 = {};   // experts 0..31
    f32x16 c1 = {};   // experts 32..63
    float sq = 0.f;

    // prologue: stage slabs 0,1; wait slab 0 (allow slab 1 in flight)
    stage_slab128(x, tb, 0, slab, w, lane);
    stage_slab128(x, tb, 128, slab + 4096, w, lane);
    __builtin_amdgcn_sched_barrier(0);
    asm volatile("s_waitcnt vmcnt(2)" ::: "memory");
    __builtin_amdgcn_sched_barrier(0);
    __builtin_amdgcn_s_barrier();
    __builtin_amdgcn_sched_barrier(0);

    int bcur = 0;
#pragma unroll 1
    for (int s = 0; s < NSLAB; ++s) {
        // B-frag loads FIRST (older than this slab's stage => their MFMA waits
        // subsume stage(s+1) readiness via in-order vmcnt retirement)
        const frag b1a = *(const frag*)(b1p);
        const frag b1b = *(const frag*)(b1p + TILE1);
        const frag b2a = *(const frag*)(b2p);
        const frag b2b = *(const frag*)(b2p + TILE1);
        const frag b3a = *(const frag*)(b3p);
        const frag b3b = *(const frag*)(b3p + TILE1);

        // stage slab s+2 into buffer (bcur+2)%3 (newest loads -> stay in flight)
        if (s < NSLAB - 2) {
            int bnxt = bcur + 2; if (bnxt >= 3) bnxt -= 3;
            stage_slab128(x, tb, (s + 2) * 128, slab + bnxt * 4096, w, lane);
        }

        // A frags from LDS (swizzled chunks)
        const float* base = slab + bcur * 4096 + roff;
        const float4 va = *(const float4*)(base + ((cA ^ sw) << 2));
        const float4 vb = *(const float4*)(base + (((cA + 1) ^ sw) << 2));

        const float vals[8] = {va.x, va.y, va.z, va.w, vb.x, vb.y, vb.z, vb.w};
        i32x4 a1i, a2i, a3i;
#pragma unroll
        for (int p = 0; p < 4; ++p) {
            const float v0 = vals[2 * p], v1 = vals[2 * p + 1];
            sq = fmaf(v0, v0, sq);
            sq = fmaf(v1, v1, sq);
            unsigned r10_, r20_, z0_, r11_, r21_, z1_;
            split3c(v0, r10_, r20_, z0_);
            split3c(v1, r11_, r21_, z1_);
            a1i[p] = (int)((r10_ >> 16) | (r11_ & 0xFFFF0000u));
            a2i[p] = (int)((r20_ >> 16) | (r21_ & 0xFFFF0000u));
            a3i[p] = (int)((z0_  >> 16) | (z1_  & 0xFFFF0000u));
        }
        const frag A1 = __builtin_bit_cast(frag, a1i);
        const frag A2 = __builtin_bit_cast(frag, a2i);
        const frag A3 = __builtin_bit_cast(frag, a3i);

        // 6 products/tile: h1h1 + (h1h2+h2h1) + (h1h3+h3h1+h2h2)
        c0 = __builtin_amdgcn_mfma_f32_32x32x16_bf16(A1, b1a, c0, 0, 0, 0);
        c1 = __builtin_amdgcn_mfma_f32_32x32x16_bf16(A1, b1b, c1, 0, 0, 0);
        c0 = __builtin_amdgcn_mfma_f32_32x32x16_bf16(A1, b2a, c0, 0, 0, 0);
        c1 = __builtin_amdgcn_mfma_f32_32x32x16_bf16(A1, b2b, c1, 0, 0, 0);
        c0 = __builtin_amdgcn_mfma_f32_32x32x16_bf16(A2, b1a, c0, 0, 0, 0);
        c1 = __builtin_amdgcn_mfma_f32_32x32x16_bf16(A2, b1b, c1, 0, 0, 0);
        c0 = __builtin_amdgcn_mfma_f32_32x32x16_bf16(A1, b3a, c0, 0, 0, 0);
        c1 = __builtin_amdgcn_mfma_f32_32x32x16_bf16(A1, b3b, c1, 0, 0, 0);
        c0 = __builtin_amdgcn_mfma_f32_32x32x16_bf16(A3, b1a, c0, 0, 0, 0);
        c1 = __builtin_amdgcn_mfma_f32_32x32x16_bf16(A3, b1b, c1, 0, 0, 0);
        c0 = __builtin_amdgcn_mfma_f32_32x32x16_bf16(A2, b2a, c0, 0, 0, 0);
        c1 = __builtin_amdgcn_mfma_f32_32x32x16_bf16(A2, b2b, c1, 0, 0, 0);

        // end-of-slab sync: vmcnt(2) allows stage(s+2)'s 2 loads to ride across
        __builtin_amdgcn_sched_barrier(0);
        asm volatile("s_waitcnt vmcnt(2)" ::: "memory");
        __builtin_amdgcn_sched_barrier(0);
        __builtin_amdgcn_s_barrier();
        __builtin_amdgcn_sched_barrier(0);

        b1p += SLABB; b2p += SLABB; b3p += SLABB;
        if (++bcur == 3) bcur = 0;
    }

    // per-token partial sumsq (lanes l and l+32 share a token)
    sq += __shfl_xor(sq, 32);
    if (lane < 32) sqred[w][l31] = sq;

    // stage 1: waves 4..7 deposit (slab LDS dead; red/res alias it)
    if (w >= 4) {
#pragma unroll
        for (int r = 0; r < 16; ++r) {
            red[w - 4][lane][r]      = c0[r];
            red[w - 4][lane][16 + r] = c1[r];
        }
    }
    __syncthreads();

    // L2-norm scale per token (full K)
    if (t < 32) {
        float q = 0.f;
#pragma unroll
        for (int ww = 0; ww < 8; ++ww) q += sqred[ww][t];
        scl[t] = SCALE / fmaxf(sqrtf(q), EPS);
    }

    // stage 2: waves 0..3 fold their registers in (thread-private cells)
    if (w < 4) {
#pragma unroll
        for (int r = 0; r < 16; ++r) {
            red[w][lane][r]      = c0[r] + red[w][lane][r];
            red[w][lane][16 + r] = c1[r] + red[w][lane][16 + r];
        }
    }
    __syncthreads();

    // gather: wave w owns regs R = 4w..4w+3 (= 16*tile + 4*wm + j);
    // token=(R&3)+8*((R&15)>>2)+4*half, expert = l31 + 32*tile
    const int wm = w & 3, tile = w >> 2;
    const int et = l31 + 32 * tile;
#pragma unroll
    for (int j = 0; j < 4; ++j) {
        const int R = 4 * w + j;
        const float a = red[0][lane][R] + red[1][lane][R] +
                        red[2][lane][R] + red[3][lane][R];
        const int token = j + 8 * wm + 4 * half;
        res[token][et] = a * scl[token];
    }
    __syncthreads();

    // coalesced outR write: thread t -> token t>>4, float4 quad t&15
    {
        const int token = t >> 4, q4 = (t & 15) * 4;
        *(float4*)(outR + (size_t)(tb + token) * NE + q4) =
            *(const float4*)(&res[token][q4]);
    }

    // fused top-8: wave w handles tokens 4w..4w+3.
    // 64-bit key = sortable(f32)<<32 | (63-e): max-reduce = highest value,
    // ties -> lowest expert index (= jax.lax.top_k order).
#pragma unroll 1
    for (int tt = 0; tt < 4; ++tt) {
        const int token = 4 * w + tt;
        const float v = res[token][lane];
        const unsigned u = __builtin_bit_cast(unsigned, v);
        const unsigned sbits = u ^ ((unsigned)(((int)u) >> 31) | 0x80000000u);
        unsigned long long cur = ((unsigned long long)sbits << 32) | (unsigned)(63 - lane);

        float bw = 0.f;
        int   bi = 0;
#pragma unroll
        for (int m = 0; m < TOPK; ++m) {
            unsigned long long r = cur;
#pragma unroll
            for (int d = 32; d >= 1; d >>= 1) {
                const unsigned long long o = __shfl_xor(r, d);
                r = (o > r) ? o : r;
            }
            const int we = 63 - (int)(r & 63ull);   // uniform across wave
            const float bv = __shfl(v, we);
            if (lane == we) cur = 0ull;             // remove winner
            if (lane == m) { bw = bv; bi = we; }
        }
        if (lane < TOPK) {
            const size_t ob = (size_t)(tb + token) * TOPK + lane;
            outW[ob] = log1pf(expf(bw));
            outI[ob] = (float)bi;
        }
    }
}

extern "C" void kernel_launch(void* const* d_in, const int* in_sizes, int n_in,
                              void* d_out, int out_size, void* d_ws, size_t ws_size,
                              hipStream_t stream) {
    const float* x   = (const float*)d_in[0];
    const float* sig = (const float*)d_in[1];
    float* out  = (float*)d_out;
    float* outW = out;
    float* outI = out + (size_t)N_TOKENS * TOPK;
    float* outR = out + (size_t)N_TOKENS * TOPK * 2;

    const size_t SIGE = (size_t)NE * DIM;   // 262144 elems per plane
    short* sh1 = (short*)d_ws;              // 3 planes = 1.5 MB total
    short* sh2 = sh1 + SIGE;
    short* sh3 = sh2 + SIGE;

    convert_sig<<<128, 256, 0, stream>>>(sig, sh1, sh2, sh3);
    gemm_fused<<<N_TOKENS / 32, 512, 0, stream>>>(x, sh1, sh2, sh3, outR, outW, outI);
}